// Round 11
// baseline (157.882 us; speedup 1.0000x reference)
//
#include <hip/hip_runtime.h>

static constexpr int NWK  = 8192;
static constexpr int NTK  = 4096;
static constexpr int HD   = 128;
static constexpr int CWW  = 256;   // cap ww row degree (mean 82, max~125)
static constexpr int CWTR = 128;   // cap wt row degree (mean 41)
static constexpr int CWTC = 256;   // cap wt col degree (mean 82)
static constexpr int QCW  = 128;   // per-wave quarter cap, ww (mean 20, max~45)
static constexpr int QCT  = 64;    // per-wave quarter cap, wt (mean 10, max~30)
static constexpr int KPB  = NWK/32 + NTK/32;   // 384 kproj blocks

typedef float  f32x4  __attribute__((ext_vector_type(4)));
typedef __bf16 bf16x8 __attribute__((ext_vector_type(8)));

__device__ __forceinline__ float b2f(unsigned short u){
  unsigned int x = ((unsigned int)u) << 16;
  return __builtin_bit_cast(float, x);
}
__device__ __forceinline__ unsigned short f2b(float x){
  return __builtin_bit_cast(unsigned short, (__bf16)x);
}
__device__ __forceinline__ float wredmax(float v){
#pragma unroll
  for(int o=32;o;o>>=1) v = fmaxf(v, __shfl_xor(v,o,64));
  return v;
}
__device__ __forceinline__ float wredsum(float v){
#pragma unroll
  for(int o=32;o;o>>=1) v += __shfl_xor(v,o,64);
  return v;
}

// ---- weight prep (W [in][out] f32 -> Wt [out][in] bf16) + zero fill/whsum
__global__ __launch_bounds__(256) void prepw(
    const float* s0,const float* s1,const float* s2,const float* s3,
    const float* s4,const float* s5,const float* s6,const float* s7,
    unsigned short* dst, int* fill, float* whsum){
  if(blockIdx.x < 16) fill[blockIdx.x*256 + threadIdx.x] = 0;
  if(blockIdx.x == 16 && threadIdx.x < 128) whsum[threadIdx.x] = 0.f;
  const float* srcs[8] = {s0,s1,s2,s3,s4,s5,s6,s7};
  int mat = blockIdx.x>>2, sl = blockIdx.x&3;
  const float* s = srcs[mat];
  unsigned short* d = dst + (size_t)mat*HD*HD;
  for(int idx=threadIdx.x + sl*4096; idx<(sl+1)*4096; idx+=256){
    int k = idx>>7, n = idx&127;
    d[n*HD+k] = f2b(s[idx]);
  }
}

// ---- one 256-col chunk: ballot compaction into LDS (no VMEM writes)
template<int CAP>
__device__ __forceinline__ void scan_chunk(
    f32x4 x, int c0base, int& base, int* __restrict__ sbuf, int lane){
  bool p0=x.x>0.f, p1=x.y>0.f, p2=x.z>0.f, p3=x.w>0.f;
  unsigned long long b0=__ballot(p0),b1=__ballot(p1),b2=__ballot(p2),b3=__ballot(p3);
  unsigned long long below = (1ull<<lane)-1ull;
  int pos = base + __popcll(b0&below)+__popcll(b1&below)+__popcll(b2&below)+__popcll(b3&below);
  int c0 = c0base + lane*4;
  if(p0){ if(pos<CAP) sbuf[pos]=c0;   pos++; }
  if(p1){ if(pos<CAP) sbuf[pos]=c0+1; pos++; }
  if(p2){ if(pos<CAP) sbuf[pos]=c0+2; pos++; }
  if(p3){ if(pos<CAP) sbuf[pos]=c0+3; pos++; }
  base += __popcll(b0)+__popcll(b1)+__popcll(b2)+__popcll(b3);
}

// ---- 2-row pipelined scan: wave w owns quarter [w*Q,(w+1)*Q) of rows A=2b,B=2b+1.
//      Burst A (NCH NT loads) then B (NCH more, 16 in flight); compact A while B's
//      loads fly; single barrier; merge/dump/scatter both rows.
template<int NCH, int QCAP, bool SCATTER>
__device__ __forceinline__ void scan_row_pair(
    const float* __restrict__ adj, long rowA, int ncols, int cap,
    int* __restrict__ idx, int* __restrict__ deg,
    int* __restrict__ cidx, int* __restrict__ fill, int ccap,
    int lane, int w, int (* __restrict__ sbufA)[QCW], int (* __restrict__ sbufB)[QCW],
    int* __restrict__ cntsA, int* __restrict__ cntsB){
  long rowB = rowA + 1;
  const int Q = NCH*256;
  const f32x4* srcA = (const f32x4*)(adj + rowA*(long)ncols) + ((w*Q)>>2);
  const f32x4* srcB = (const f32x4*)(adj + rowB*(long)ncols) + ((w*Q)>>2);
  f32x4 vA[NCH], vB[NCH];
#pragma unroll
  for(int c=0;c<NCH;c++) vA[c] = __builtin_nontemporal_load(&srcA[c*64 + lane]);
#pragma unroll
  for(int c=0;c<NCH;c++) vB[c] = __builtin_nontemporal_load(&srcB[c*64 + lane]);
  int baseA = 0;
#pragma unroll
  for(int c=0;c<NCH;c++)
    scan_chunk<QCAP>(vA[c], w*Q + c*256, baseA, sbufA[w], lane);
  int cntA = baseA<QCAP ? baseA : QCAP;
  if(lane==0) cntsA[w] = cntA;
  int baseB = 0;
#pragma unroll
  for(int c=0;c<NCH;c++)
    scan_chunk<QCAP>(vB[c], w*Q + c*256, baseB, sbufB[w], lane);
  int cntB = baseB<QCAP ? baseB : QCAP;
  if(lane==0) cntsB[w] = cntB;
  __syncthreads();
  {
    int c0=cntsA[0], c1=cntsA[1], c2=cntsA[2], c3=cntsA[3];
    int off = (w>0?c0:0) + (w>1?c1:0) + (w>2?c2:0);
    int tot = c0+c1+c2+c3;
    if(w==0 && lane==0) deg[rowA] = tot<cap ? tot : cap;
    int* orow = idx + rowA*(long)cap;
    for(int k=lane; k<cntA; k+=64){
      int p = off+k;
      if(p<cap) orow[p] = sbufA[w][k];
    }
    if(SCATTER){
      for(int k=lane; k<cntA; k+=64){
        int task = sbufA[w][k];
        int pp = atomicAdd(&fill[task], 1);
        if(pp < ccap) cidx[(long)task*ccap + pp] = (int)rowA;
      }
    }
  }
  {
    int c0=cntsB[0], c1=cntsB[1], c2=cntsB[2], c3=cntsB[3];
    int off = (w>0?c0:0) + (w>1?c1:0) + (w>2?c2:0);
    int tot = c0+c1+c2+c3;
    if(w==0 && lane==0) deg[rowB] = tot<cap ? tot : cap;
    int* orow = idx + rowB*(long)cap;
    for(int k=lane; k<cntB; k+=64){
      int p = off+k;
      if(p<cap) orow[p] = sbufB[w][k];
    }
    if(SCATTER){
      for(int k=lane; k<cntB; k+=64){
        int task = sbufB[w][k];
        int pp = atomicAdd(&fill[task], 1);
        if(pp < ccap) cidx[(long)task*ccap + pp] = (int)rowB;
      }
    }
  }
}

// ---- kproj body: h = relu(X@Wp + b), output bf16
__device__ __forceinline__ void kproj_body(
    int bk, const float* __restrict__ Xw, const float* __restrict__ Xt,
    const unsigned short* __restrict__ Wtb,
    const float* __restrict__ bp_w, const float* __restrict__ bp_t,
    unsigned short* __restrict__ h_w, unsigned short* __restrict__ h_t,
    __bf16* As){
  bool task = bk >= (NWK/32);
  const float* X = task ? Xt : Xw;
  const __bf16* Wt = (const __bf16*)(Wtb + (size_t)(task?1:0)*HD*HD);
  const float* bias = task ? bp_t : bp_w;
  unsigned short* H = task ? h_t : h_w;
  long r0 = (long)(task ? bk-(NWK/32) : bk)*32;

  char* Ab = (char*)As;
  int t = threadIdx.x, lane = t&63, w = t>>6;
  const float4* A4 = (const float4*)(X + r0*HD);
#pragma unroll
  for(int i=0;i<4;i++){
    int id = t + i*256;
    float4 v = A4[id];
    int row = id>>5, c4 = id&31;
    int byte = row*256 + c4*8;
    ushort4 b; b.x=f2b(v.x); b.y=f2b(v.y); b.z=f2b(v.z); b.w=f2b(v.w);
    *(ushort4*)(Ab + (byte ^ ((row&7)<<4))) = b;
  }
  __syncthreads();
  f32x4 acc[2][2] = {};
  int n0 = w*32;
#pragma unroll
  for(int kk=0;kk<4;kk++){
    int kb = kk*32 + (lane>>4)*8;
    bf16x8 bf0 = *(const bf16x8*)(Wt + (n0 +      (lane&15))*HD + kb);
    bf16x8 bf1 = *(const bf16x8*)(Wt + (n0 + 16 + (lane&15))*HD + kb);
#pragma unroll
    for(int m=0;m<2;m++){
      int row = m*16 + (lane&15);
      bf16x8 af = *(const bf16x8*)(Ab + ((row*256 + kb*2) ^ ((row&7)<<4)));
      acc[m][0] = __builtin_amdgcn_mfma_f32_16x16x32_bf16(af, bf0, acc[m][0], 0,0,0);
      acc[m][1] = __builtin_amdgcn_mfma_f32_16x16x32_bf16(af, bf1, acc[m][1], 0,0,0);
    }
  }
#pragma unroll
  for(int m=0;m<2;m++)
#pragma unroll
  for(int n=0;n<2;n++){
    int col = n0 + n*16 + (lane&15);
    float bc = bias[col];
#pragma unroll
    for(int i=0;i<4;i++){
      long row = r0 + m*16 + (lane>>4)*4 + i;
      float vv = acc[m][n][i] + bc;
      vv = vv>0.f ? vv : 0.f;
      H[row*HD+col] = f2b(vv);
    }
  }
}

// ---- fused front: kproj blocks first (overlap), then WW / WT 2-row scans
__global__ __launch_bounds__(256) void fused_front(
    const float* __restrict__ WW, const float* __restrict__ WT,
    int* __restrict__ ww_idx, int* __restrict__ ww_deg,
    int* __restrict__ wt_idx, int* __restrict__ wt_deg,
    int* __restrict__ cidx, int* __restrict__ fill,
    const float* __restrict__ Xw, const float* __restrict__ Xt,
    const unsigned short* __restrict__ Wtb,
    const float* __restrict__ bp_w, const float* __restrict__ bp_t,
    unsigned short* __restrict__ h_w, unsigned short* __restrict__ h_t){
  __shared__ int sbufA[4][QCW];      // 2 KB
  __shared__ int sbufB[4][QCW];      // 2 KB
  __shared__ int cntsA[4], cntsB[4];
  __shared__ __bf16 As[32*HD];       // 8 KB (kproj path)
  int lane = threadIdx.x&63, w = threadIdx.x>>6;
  int b = blockIdx.x;
  if(b < KPB){
    kproj_body(b, Xw, Xt, Wtb, bp_w, bp_t, h_w, h_t, As);
  } else if(b < KPB + NWK/2){
    long rowA = (long)(b - KPB)*2;
    scan_row_pair<8,QCW,false>(WW, rowA, NWK, CWW, ww_idx, ww_deg,
                               nullptr, nullptr, 0, lane, w, sbufA, sbufB, cntsA, cntsB);
  } else {
    long rowA = (long)(b - KPB - NWK/2)*2;
    scan_row_pair<4,QCT,true>(WT, rowA, NTK, CWTR, wt_idx, wt_deg,
                              cidx, fill, CWTC, lane, w, sbufA, sbufB, cntsA, cntsB);
  }
}

// ---- gather-sum of a bf16 [*,128] table over an index list (4-wide unrolled)
__device__ __forceinline__ void gather_sum(
    const unsigned short* __restrict__ tab, const int* __restrict__ ji, int d,
    int lane, float& ax, float& ay){
  int k=0;
  for(; k+3<d; k+=4){
    long j0=ji[k], j1=ji[k+1], j2=ji[k+2], j3=ji[k+3];
    ushort2 u0 = *(const ushort2*)(tab + j0*HD + lane*2);
    ushort2 u1 = *(const ushort2*)(tab + j1*HD + lane*2);
    ushort2 u2 = *(const ushort2*)(tab + j2*HD + lane*2);
    ushort2 u3 = *(const ushort2*)(tab + j3*HD + lane*2);
    ax += (b2f(u0.x)+b2f(u1.x)) + (b2f(u2.x)+b2f(u3.x));
    ay += (b2f(u0.y)+b2f(u1.y)) + (b2f(u2.y)+b2f(u3.y));
  }
  for(; k<d; ++k){
    long j0=ji[k];
    ushort2 u0 = *(const ushort2*)(tab + j0*HD + lane*2);
    ax += b2f(u0.x); ay += b2f(u0.y);
  }
}

// ---- aggregate raw h
__global__ __launch_bounds__(256) void agg(
    const unsigned short* __restrict__ h_w, const unsigned short* __restrict__ h_t,
    const int* __restrict__ wwidx, const int* __restrict__ wwdeg,
    const int* __restrict__ wtidx, const int* __restrict__ wtdeg,
    const int* __restrict__ cidx,  const int* __restrict__ fill,
    unsigned short* __restrict__ g_ww, unsigned short* __restrict__ g_tw,
    unsigned short* __restrict__ g_wt){
  int w = threadIdx.x>>6, lane = threadIdx.x&63;
  long i = (long)blockIdx.x*4 + w;
  if(i < NWK){
    float ax=0.f, ay=0.f;
    gather_sum(h_w, wwidx + i*CWW, wwdeg[i], lane, ax, ay);
    ushort2 o; o.x=f2b(ax); o.y=f2b(ay);
    *(ushort2*)(g_ww + i*HD + lane*2) = o;
    ax=0.f; ay=0.f;
    gather_sum(h_t, wtidx + i*CWTR, wtdeg[i], lane, ax, ay);
    o.x=f2b(ax); o.y=f2b(ay);
    *(ushort2*)(g_tw + i*HD + lane*2) = o;
  } else {
    long tt = i - NWK;
    float ax=0.f, ay=0.f;
    int d = fill[tt]; if(d>CWTC) d=CWTC;
    gather_sum(h_w, cidx + tt*CWTC, d, lane, ax, ay);
    ushort2 o; o.x=f2b(ax); o.y=f2b(ay);
    *(ushort2*)(g_wt + tt*HD + lane*2) = o;
  }
}

// ---- stage a 32x128 bf16 tile into swizzled LDS
__device__ __forceinline__ void stage_bf16(char* Ab, const unsigned short* src, int t){
#pragma unroll
  for(int i=0;i<2;i++){
    int id = t + i*256;
    int row = id>>4, c8 = id&15;
    bf16x8 v = *(const bf16x8*)(src + row*HD + c8*8);
    int byte = row*256 + c8*16;
    *(bf16x8*)(Ab + (byte ^ ((row&7)<<4))) = v;
  }
}

// ---- RGCN + IGAT fused
__global__ __launch_bounds__(256) void krgcn(
    const unsigned short* __restrict__ h_w, const unsigned short* __restrict__ h_t,
    const unsigned short* __restrict__ g_ww, const unsigned short* __restrict__ g_tw,
    const unsigned short* __restrict__ g_wt,
    const unsigned short* __restrict__ Wtb,
    const float* __restrict__ b_worker, const float* __restrict__ b_task,
    const float* __restrict__ a_src, const float* __restrict__ a_dst,
    unsigned short* __restrict__ Wh, float* __restrict__ fs, float* __restrict__ fd,
    float* __restrict__ whsum, float* __restrict__ out_task){
  __shared__ __bf16 As[3][32*HD];    // 24 KB
  __shared__ __bf16 Hs[32*HD];       // 8 KB
  __shared__ float fsp[32][4], fdp[32][4];
  int t = threadIdx.x, lane = t&63, w = t>>6, n0 = w*32;
  bool task = blockIdx.x >= (NWK/32);

  if(!task){
    long r0 = (long)blockIdx.x*32;
    stage_bf16((char*)As[0], h_w  + r0*HD, t);
    stage_bf16((char*)As[1], g_ww + r0*HD, t);
    stage_bf16((char*)As[2], g_tw + r0*HD, t);
    __syncthreads();
    f32x4 acc[2][2] = {};
    const int slot[3] = {2,4,6};     // W_worker, W_ww, W_tw
#pragma unroll
    for(int s=0;s<3;s++){
      const __bf16* Wt = (const __bf16*)(Wtb + (size_t)slot[s]*HD*HD);
      char* Ab = (char*)As[s];
#pragma unroll
      for(int kk=0;kk<4;kk++){
        int kb = kk*32 + (lane>>4)*8;
        bf16x8 bf0 = *(const bf16x8*)(Wt + (n0 +      (lane&15))*HD + kb);
        bf16x8 bf1 = *(const bf16x8*)(Wt + (n0 + 16 + (lane&15))*HD + kb);
#pragma unroll
        for(int m=0;m<2;m++){
          int row = m*16 + (lane&15);
          bf16x8 af = *(const bf16x8*)(Ab + ((row*256 + kb*2) ^ ((row&7)<<4)));
          acc[m][0] = __builtin_amdgcn_mfma_f32_16x16x32_bf16(af, bf0, acc[m][0], 0,0,0);
          acc[m][1] = __builtin_amdgcn_mfma_f32_16x16x32_bf16(af, bf1, acc[m][1], 0,0,0);
        }
      }
    }
    char* HsB = (char*)Hs;
#pragma unroll
    for(int m=0;m<2;m++)
#pragma unroll
    for(int n=0;n<2;n++){
      int col = n0 + n*16 + (lane&15);
      float bc = b_worker[col];
#pragma unroll
      for(int i=0;i<4;i++){
        int row = m*16 + (lane>>4)*4 + i;
        float vv = acc[m][n][i] + bc;
        vv = vv>0.f ? vv : 0.f;
        int byte = row*256 + col*2;
        *(__bf16*)(HsB + (byte ^ ((row&7)<<4))) = (__bf16)vv;
      }
    }
    __syncthreads();
    // stage2: Wh = hwr @ W_igat
    f32x4 acc2[2][2] = {};
    const __bf16* Wt7 = (const __bf16*)(Wtb + (size_t)7*HD*HD);
#pragma unroll
    for(int kk=0;kk<4;kk++){
      int kb = kk*32 + (lane>>4)*8;
      bf16x8 bf0 = *(const bf16x8*)(Wt7 + (n0 +      (lane&15))*HD + kb);
      bf16x8 bf1 = *(const bf16x8*)(Wt7 + (n0 + 16 + (lane&15))*HD + kb);
#pragma unroll
      for(int m=0;m<2;m++){
        int row = m*16 + (lane&15);
        bf16x8 af = *(const bf16x8*)(HsB + ((row*256 + kb*2) ^ ((row&7)<<4)));
        acc2[m][0] = __builtin_amdgcn_mfma_f32_16x16x32_bf16(af, bf0, acc2[m][0], 0,0,0);
        acc2[m][1] = __builtin_amdgcn_mfma_f32_16x16x32_bf16(af, bf1, acc2[m][1], 0,0,0);
      }
    }
#pragma unroll
    for(int m=0;m<2;m++)
#pragma unroll
    for(int n=0;n<2;n++){
      int col = n0 + n*16 + (lane&15);
#pragma unroll
      for(int i=0;i<4;i++){
        long row = r0 + m*16 + (lane>>4)*4 + i;
        Wh[row*HD+col] = f2b(acc2[m][n][i]);
      }
    }
    // fs/fd: per-wave 32-col partials -> LDS -> block reduce, direct store
    float as0 = a_src[n0 + (lane&15)], as1 = a_src[n0 + 16 + (lane&15)];
    float ad0 = a_dst[n0 + (lane&15)], ad1 = a_dst[n0 + 16 + (lane&15)];
#pragma unroll
    for(int m=0;m<2;m++)
#pragma unroll
    for(int i=0;i<4;i++){
      float ps = acc2[m][0][i]*as0 + acc2[m][1][i]*as1;
      float pd = acc2[m][0][i]*ad0 + acc2[m][1][i]*ad1;
#pragma unroll
      for(int o=1;o<16;o<<=1){ ps += __shfl_xor(ps,o,64); pd += __shfl_xor(pd,o,64); }
      if((lane&15)==0){
        int row = m*16 + (lane>>4)*4 + i;
        fsp[row][w] = ps; fdp[row][w] = pd;
      }
    }
    // whsum column partial (deg-0 fallback)
    float c0=0.f, c1=0.f;
#pragma unroll
    for(int m=0;m<2;m++)
#pragma unroll
    for(int i=0;i<4;i++){ c0 += acc2[m][0][i]; c1 += acc2[m][1][i]; }
    c0 += __shfl_xor(c0,16,64); c0 += __shfl_xor(c0,32,64);
    c1 += __shfl_xor(c1,16,64); c1 += __shfl_xor(c1,32,64);
    if(lane<16){
      atomicAdd(&whsum[n0+lane],    c0);
      atomicAdd(&whsum[n0+16+lane], c1);
    }
    __syncthreads();
    if(t < 32){
      fs[r0+t] = fsp[t][0]+fsp[t][1]+fsp[t][2]+fsp[t][3];
      fd[r0+t] = fdp[t][0]+fdp[t][1]+fdp[t][2]+fdp[t][3];
    }
  } else {
    long r0 = (long)(blockIdx.x - (NWK/32))*32;
    stage_bf16((char*)As[0], h_t  + r0*HD, t);
    stage_bf16((char*)As[1], g_wt + r0*HD, t);
    __syncthreads();
    f32x4 acc[2][2] = {};
    const int slot[2] = {3,5};       // W_task, W_wt
#pragma unroll
    for(int s=0;s<2;s++){
      const __bf16* Wt = (const __bf16*)(Wtb + (size_t)slot[s]*HD*HD);
      char* Ab = (char*)As[s];
#pragma unroll
      for(int kk=0;kk<4;kk++){
        int kb = kk*32 + (lane>>4)*8;
        bf16x8 bf0 = *(const bf16x8*)(Wt + (n0 +      (lane&15))*HD + kb);
        bf16x8 bf1 = *(const bf16x8*)(Wt + (n0 + 16 + (lane&15))*HD + kb);
#pragma unroll
        for(int m=0;m<2;m++){
          int row = m*16 + (lane&15);
          bf16x8 af = *(const bf16x8*)(Ab + ((row*256 + kb*2) ^ ((row&7)<<4)));
          acc[m][0] = __builtin_amdgcn_mfma_f32_16x16x32_bf16(af, bf0, acc[m][0], 0,0,0);
          acc[m][1] = __builtin_amdgcn_mfma_f32_16x16x32_bf16(af, bf1, acc[m][1], 0,0,0);
        }
      }
    }
#pragma unroll
    for(int m=0;m<2;m++)
#pragma unroll
    for(int n=0;n<2;n++){
      int col = n0 + n*16 + (lane&15);
      float bc = b_task[col];
#pragma unroll
      for(int i=0;i<4;i++){
        long row = r0 + m*16 + (lane>>4)*4 + i;
        float vv = acc[m][n][i] + bc;
        vv = vv>0.f ? vv : 0.f;
        vv += b2f(h_t[row*HD+col]);
        out_task[row*HD+col] = vv;
      }
    }
  }
}

// ---- sparse masked attention + ELU + residual -> final_worker
__global__ __launch_bounds__(256) void attn(
    const unsigned short* __restrict__ Wh, const float* __restrict__ fs,
    const float* __restrict__ fd, const int* __restrict__ idx,
    const int* __restrict__ deg, const unsigned short* __restrict__ h_w,
    const float* __restrict__ whsum, float* __restrict__ out){
  __shared__ float pa[4][CWW];
  __shared__ int   pj[4][CWW];
  int w = threadIdx.x>>6, lane = threadIdx.x&63;
  long i = (long)blockIdx.x*4 + w;
  int d = deg[i];
  const int* ji = idx + i*CWW;
  float ax=0.f, ay=0.f;
  if(d > 0){
    float fsi = fs[i];
    float m = -1e30f;
    for(int k=lane;k<d;k+=64){
      int j = ji[k]; pj[w][k] = j;
      float e = fsi + fd[j];
      e = e>0.f ? e : 0.2f*e;
      pa[w][k] = e;
      m = fmaxf(m, e);
    }
    m = wredmax(m);
    float ssum = 0.f;
    for(int k=lane;k<d;k+=64){
      float e = __expf(pa[w][k]-m);
      pa[w][k] = e;
      ssum += e;
    }
    ssum = wredsum(ssum);
    float inv = 1.f/ssum;
    int k=0;
    for(; k+3<d; k+=4){
      float a0=pa[w][k], a1=pa[w][k+1], a2=pa[w][k+2], a3=pa[w][k+3];
      long j0=pj[w][k], j1=pj[w][k+1], j2=pj[w][k+2], j3=pj[w][k+3];
      ushort2 u0 = *(const ushort2*)(Wh + j0*HD + lane*2);
      ushort2 u1 = *(const ushort2*)(Wh + j1*HD + lane*2);
      ushort2 u2 = *(const ushort2*)(Wh + j2*HD + lane*2);
      ushort2 u3 = *(const ushort2*)(Wh + j3*HD + lane*2);
      ax += (a0*b2f(u0.x) + a1*b2f(u1.x)) + (a2*b2f(u2.x) + a3*b2f(u3.x));
      ay += (a0*b2f(u0.y) + a1*b2f(u1.y)) + (a2*b2f(u2.y) + a3*b2f(u3.y));
    }
    for(; k<d; ++k){
      float a0 = pa[w][k];
      long j0 = pj[w][k];
      ushort2 u0 = *(const ushort2*)(Wh + j0*HD + lane*2);
      ax += a0*b2f(u0.x);
      ay += a0*b2f(u0.y);
    }
    ax *= inv; ay *= inv;
  } else {
    ax = whsum[lane*2]   * (1.f/8192.f);
    ay = whsum[lane*2+1] * (1.f/8192.f);
  }
  ushort2 r = *(const ushort2*)(h_w + i*HD + lane*2);
  float2 o;
  o.x = (ax>0.f ? ax : __expf(ax)-1.f) + b2f(r.x);
  o.y = (ay>0.f ? ay : __expf(ay)-1.f) + b2f(r.y);
  *(float2*)(out + i*HD + lane*2) = o;
}

extern "C" void kernel_launch(void* const* d_in, const int* in_sizes, int n_in,
                              void* d_out, int out_size, void* d_ws, size_t ws_size,
                              hipStream_t stream){
  const float* Xw       = (const float*)d_in[0];
  const float* Xt       = (const float*)d_in[1];
  const float* WW       = (const float*)d_in[2];
  const float* WT       = (const float*)d_in[3];
  const float* Wp_w     = (const float*)d_in[4];
  const float* bp_w     = (const float*)d_in[5];
  const float* Wp_t     = (const float*)d_in[6];
  const float* bp_t     = (const float*)d_in[7];
  const float* W_worker = (const float*)d_in[8];
  const float* b_worker = (const float*)d_in[9];
  const float* W_task   = (const float*)d_in[10];
  const float* b_task   = (const float*)d_in[11];
  const float* W_ww     = (const float*)d_in[12];
  const float* W_wt     = (const float*)d_in[13];
  const float* W_tw     = (const float*)d_in[14];
  const float* W_igat   = (const float*)d_in[15];
  const float* a_src    = (const float*)d_in[16];
  const float* a_dst    = (const float*)d_in[17];
  float* out = (float*)d_out;

  char* p = (char*)d_ws;
  auto alloc = [&](size_t bytes)->char*{
    char* r = p; p += (bytes + 255) & ~(size_t)255; return r;
  };
  int* ww_idx  = (int*)alloc((size_t)NWK*CWW*4);
  int* wt_idx  = (int*)alloc((size_t)NWK*CWTR*4);
  int* wt_cidx = (int*)alloc((size_t)NTK*CWTC*4);
  int* ww_deg  = (int*)alloc(NWK*4);
  int* wt_deg  = (int*)alloc(NWK*4);
  int*   fill  = (int*)alloc(NTK*4);
  float* whsum = (float*)alloc(512);
  float* fs    = (float*)alloc(NWK*4);
  float* fd    = (float*)alloc(NWK*4);
  unsigned short* h_w  = (unsigned short*)alloc((size_t)NWK*HD*2);
  unsigned short* h_t  = (unsigned short*)alloc((size_t)NTK*HD*2);
  unsigned short* g_ww = (unsigned short*)alloc((size_t)NWK*HD*2);
  unsigned short* g_tw = (unsigned short*)alloc((size_t)NWK*HD*2);
  unsigned short* g_wt = (unsigned short*)alloc((size_t)NTK*HD*2);
  unsigned short* Wh   = (unsigned short*)alloc((size_t)NWK*HD*2);
  unsigned short* Wtb  = (unsigned short*)alloc((size_t)8*HD*HD*2);

  prepw<<<32,256,0,stream>>>(Wp_w, Wp_t, W_worker, W_task, W_ww, W_wt, W_tw, W_igat,
                             Wtb, fill, whsum);
  fused_front<<<KPB + NWK,256,0,stream>>>(WW, WT, ww_idx, ww_deg, wt_idx, wt_deg,
                                          wt_cidx, fill, Xw, Xt, Wtb, bp_w, bp_t,
                                          h_w, h_t);
  agg<<<(NWK+NTK)/4,256,0,stream>>>(h_w, h_t, ww_idx, ww_deg, wt_idx, wt_deg,
                                    wt_cidx, fill, g_ww, g_tw, g_wt);
  krgcn<<<NWK/32 + NTK/32,256,0,stream>>>(h_w, h_t, g_ww, g_tw, g_wt, Wtb,
                                          b_worker, b_task, a_src, a_dst,
                                          Wh, fs, fd, whsum, out + (size_t)NWK*HD);
  attn<<<NWK/4,256,0,stream>>>(Wh, fs, fd, ww_idx, ww_deg, h_w, whsum, out);
}

// Round 12
// 144.095 us; speedup vs baseline: 1.0957x; 1.0957x over previous
//
#include <hip/hip_runtime.h>

static constexpr int NWK  = 8192;
static constexpr int NTK  = 4096;
static constexpr int HD   = 128;
static constexpr int CWW  = 256;   // cap ww row degree (mean 82, max~125)
static constexpr int CWTR = 128;   // cap wt row degree (mean 41)
static constexpr int CWTC = 256;   // cap wt col degree (mean 82)
static constexpr int QCW  = 128;   // per-wave quarter cap, ww (mean 20, max~45)
static constexpr int QCT  = 64;    // per-wave quarter cap, wt (mean 10, max~30)

typedef float  f32x4  __attribute__((ext_vector_type(4)));
typedef __bf16 bf16x8 __attribute__((ext_vector_type(8)));

__device__ __forceinline__ float b2f(unsigned short u){
  unsigned int x = ((unsigned int)u) << 16;
  return __builtin_bit_cast(float, x);
}
__device__ __forceinline__ unsigned short f2b(float x){
  return __builtin_bit_cast(unsigned short, (__bf16)x);
}
__device__ __forceinline__ float wredmax(float v){
#pragma unroll
  for(int o=32;o;o>>=1) v = fmaxf(v, __shfl_xor(v,o,64));
  return v;
}
__device__ __forceinline__ float wredsum(float v){
#pragma unroll
  for(int o=32;o;o>>=1) v += __shfl_xor(v,o,64);
  return v;
}

// ---- weight prep (W [in][out] f32 -> Wt [out][in] bf16) + zero fill/whsum
__global__ __launch_bounds__(256) void prepw(
    const float* s0,const float* s1,const float* s2,const float* s3,
    const float* s4,const float* s5,const float* s6,const float* s7,
    unsigned short* dst, int* fill, float* whsum){
  if(blockIdx.x < 16) fill[blockIdx.x*256 + threadIdx.x] = 0;
  if(blockIdx.x == 16 && threadIdx.x < 128) whsum[threadIdx.x] = 0.f;
  const float* srcs[8] = {s0,s1,s2,s3,s4,s5,s6,s7};
  int mat = blockIdx.x>>2, sl = blockIdx.x&3;
  const float* s = srcs[mat];
  unsigned short* d = dst + (size_t)mat*HD*HD;
  for(int idx=threadIdx.x + sl*4096; idx<(sl+1)*4096; idx+=256){
    int k = idx>>7, n = idx&127;
    d[n*HD+k] = f2b(s[idx]);
  }
}

// ---- gather-sum of a bf16 [*,128] table over an index list (4-wide unrolled)
__device__ __forceinline__ void gather_sum(
    const unsigned short* __restrict__ tab, const int* __restrict__ ji, int d,
    int lane, float& ax, float& ay){
  int k=0;
  for(; k+3<d; k+=4){
    long j0=ji[k], j1=ji[k+1], j2=ji[k+2], j3=ji[k+3];
    ushort2 u0 = *(const ushort2*)(tab + j0*HD + lane*2);
    ushort2 u1 = *(const ushort2*)(tab + j1*HD + lane*2);
    ushort2 u2 = *(const ushort2*)(tab + j2*HD + lane*2);
    ushort2 u3 = *(const ushort2*)(tab + j3*HD + lane*2);
    ax += (b2f(u0.x)+b2f(u1.x)) + (b2f(u2.x)+b2f(u3.x));
    ay += (b2f(u0.y)+b2f(u1.y)) + (b2f(u2.y)+b2f(u3.y));
  }
  for(; k<d; ++k){
    long j0=ji[k];
    ushort2 u0 = *(const ushort2*)(tab + j0*HD + lane*2);
    ax += b2f(u0.x); ay += b2f(u0.y);
  }
}

// ---- one 256-col chunk: ballot compaction into LDS (no VMEM writes)
template<int CAP>
__device__ __forceinline__ void scan_chunk(
    f32x4 x, int c0base, int& base, int* __restrict__ sbuf, int lane){
  bool p0=x.x>0.f, p1=x.y>0.f, p2=x.z>0.f, p3=x.w>0.f;
  unsigned long long b0=__ballot(p0),b1=__ballot(p1),b2=__ballot(p2),b3=__ballot(p3);
  unsigned long long below = (1ull<<lane)-1ull;
  int pos = base + __popcll(b0&below)+__popcll(b1&below)+__popcll(b2&below)+__popcll(b3&below);
  int c0 = c0base + lane*4;
  if(p0){ if(pos<CAP) sbuf[pos]=c0;   pos++; }
  if(p1){ if(pos<CAP) sbuf[pos]=c0+1; pos++; }
  if(p2){ if(pos<CAP) sbuf[pos]=c0+2; pos++; }
  if(p3){ if(pos<CAP) sbuf[pos]=c0+3; pos++; }
  base += __popcll(b0)+__popcll(b1)+__popcll(b2)+__popcll(b3);
}

// ---- block-per-row adjacency scan + FUSED row-gather:
//      wave w NT-bursts its quarter, compacts into LDS, then (indices on-chip)
//      gathers htab rows over its quarter list -> per-wave partials -> LDS
//      reduce -> g[row]. The L2 gathers hide in the NT stream's latency slack.
template<int NCH, int QCAP, bool SCATTER>
__device__ __forceinline__ void scan_row_block(
    const float* __restrict__ adj, long row, int ncols, int cap,
    int* __restrict__ orow, int* __restrict__ deg,
    int* __restrict__ cidx, int* __restrict__ fill, int ccap,
    const unsigned short* __restrict__ htab, unsigned short* __restrict__ grow,
    int lane, int w, int tid,
    int (* __restrict__ sbuf)[QCW], float (* __restrict__ gpart)[HD],
    int* __restrict__ cnts){
  const int Q = NCH*256;
  const f32x4* src = (const f32x4*)(adj + row*(long)ncols) + ((w*Q)>>2);
  f32x4 v[NCH];
#pragma unroll
  for(int c=0;c<NCH;c++) v[c] = __builtin_nontemporal_load(&src[c*64 + lane]);
  int base = 0;
#pragma unroll
  for(int c=0;c<NCH;c++)
    scan_chunk<QCAP>(v[c], w*Q + c*256, base, sbuf[w], lane);
  int cnt = base<QCAP ? base : QCAP;
  if(lane==0) cnts[w] = cnt;
  // fused gather over own quarter list (L2-resident h table)
  float ax=0.f, ay=0.f;
  gather_sum(htab, sbuf[w], cnt, lane, ax, ay);
  gpart[w][lane*2]   = ax;
  gpart[w][lane*2+1] = ay;
  __syncthreads();
  int c0=cnts[0], c1=cnts[1], c2=cnts[2], c3=cnts[3];
  int off = (w>0?c0:0) + (w>1?c1:0) + (w>2?c2:0);
  int tot = c0+c1+c2+c3;
  if(w==0 && lane==0) deg[row] = tot<cap ? tot : cap;
  for(int k=lane; k<cnt; k+=64){
    int p = off+k;
    if(p<cap) orow[p] = sbuf[w][k];
  }
  if(tid < 128){
    float s = gpart[0][tid]+gpart[1][tid]+gpart[2][tid]+gpart[3][tid];
    grow[tid] = f2b(s);
  }
  if(SCATTER){
    for(int k=lane; k<cnt; k+=64){
      int task = sbuf[w][k];
      int pp = atomicAdd(&fill[task], 1);
      if(pp < ccap) cidx[(long)task*ccap + pp] = (int)row;
    }
  }
}

__global__ __launch_bounds__(256) void build_all(
    const float* __restrict__ WW, const float* __restrict__ WT,
    int* __restrict__ ww_idx, int* __restrict__ ww_deg,
    int* __restrict__ wt_idx, int* __restrict__ wt_deg,
    int* __restrict__ cidx, int* __restrict__ fill,
    const unsigned short* __restrict__ h_w, const unsigned short* __restrict__ h_t,
    unsigned short* __restrict__ g_ww, unsigned short* __restrict__ g_tw){
  __shared__ int   sbuf[4][QCW];     // 2 KB compaction buffers
  __shared__ float gpart[4][HD];     // 2 KB gather partials
  __shared__ int   cnts[4];
  int lane = threadIdx.x&63, w = threadIdx.x>>6, tid = threadIdx.x;
  int b = blockIdx.x;
  if(b < NWK){
    long row = b;
    scan_row_block<8,QCW,false>(WW, row, NWK, CWW, ww_idx + row*CWW, ww_deg,
                                nullptr, nullptr, 0, h_w, g_ww + row*HD,
                                lane, w, tid, sbuf, gpart, cnts);
  } else {
    long row = b - NWK;              // wt has NWK rows (one per worker)
    scan_row_block<4,QCT,true>(WT, row, NTK, CWTR, wt_idx + row*CWTR, wt_deg,
                               cidx, fill, CWTC, h_t, g_tw + row*HD,
                               lane, w, tid, sbuf, gpart, cnts);
  }
}

// ---- fused projections: h = relu(X@Wp + b), output bf16
__global__ __launch_bounds__(256) void kproj(
    const float* __restrict__ Xw, const float* __restrict__ Xt,
    const unsigned short* __restrict__ Wtb,
    const float* __restrict__ bp_w, const float* __restrict__ bp_t,
    unsigned short* __restrict__ h_w, unsigned short* __restrict__ h_t){
  bool task = blockIdx.x >= (NWK/32);
  const float* X = task ? Xt : Xw;
  const __bf16* Wt = (const __bf16*)(Wtb + (size_t)(task?1:0)*HD*HD);
  const float* bias = task ? bp_t : bp_w;
  unsigned short* H = task ? h_t : h_w;
  long r0 = (long)(task ? blockIdx.x-(NWK/32) : blockIdx.x)*32;

  __shared__ __bf16 As[32*HD];
  char* Ab = (char*)As;
  int t = threadIdx.x, lane = t&63, w = t>>6;
  const float4* A4 = (const float4*)(X + r0*HD);
#pragma unroll
  for(int i=0;i<4;i++){
    int id = t + i*256;
    float4 v = A4[id];
    int row = id>>5, c4 = id&31;
    int byte = row*256 + c4*8;
    ushort4 b; b.x=f2b(v.x); b.y=f2b(v.y); b.z=f2b(v.z); b.w=f2b(v.w);
    *(ushort4*)(Ab + (byte ^ ((row&7)<<4))) = b;
  }
  __syncthreads();
  f32x4 acc[2][2] = {};
  int n0 = w*32;
#pragma unroll
  for(int kk=0;kk<4;kk++){
    int kb = kk*32 + (lane>>4)*8;
    bf16x8 bf0 = *(const bf16x8*)(Wt + (n0 +      (lane&15))*HD + kb);
    bf16x8 bf1 = *(const bf16x8*)(Wt + (n0 + 16 + (lane&15))*HD + kb);
#pragma unroll
    for(int m=0;m<2;m++){
      int row = m*16 + (lane&15);
      bf16x8 af = *(const bf16x8*)(Ab + ((row*256 + kb*2) ^ ((row&7)<<4)));
      acc[m][0] = __builtin_amdgcn_mfma_f32_16x16x32_bf16(af, bf0, acc[m][0], 0,0,0);
      acc[m][1] = __builtin_amdgcn_mfma_f32_16x16x32_bf16(af, bf1, acc[m][1], 0,0,0);
    }
  }
#pragma unroll
  for(int m=0;m<2;m++)
#pragma unroll
  for(int n=0;n<2;n++){
    int col = n0 + n*16 + (lane&15);
    float bc = bias[col];
#pragma unroll
    for(int i=0;i<4;i++){
      long row = r0 + m*16 + (lane>>4)*4 + i;
      float vv = acc[m][n][i] + bc;
      vv = vv>0.f ? vv : 0.f;
      H[row*HD+col] = f2b(vv);
    }
  }
}

// ---- task-side CSC gather: g_wt[t] = sum_{w in CSC(t)} h_w[w]
__global__ __launch_bounds__(256) void agg_csc(
    const unsigned short* __restrict__ h_w, const int* __restrict__ cidx,
    const int* __restrict__ fill, unsigned short* __restrict__ g_wt){
  int w = threadIdx.x>>6, lane = threadIdx.x&63;
  long tt = (long)blockIdx.x*4 + w;
  float ax=0.f, ay=0.f;
  int d = fill[tt]; if(d>CWTC) d=CWTC;
  gather_sum(h_w, cidx + tt*CWTC, d, lane, ax, ay);
  ushort2 o; o.x=f2b(ax); o.y=f2b(ay);
  *(ushort2*)(g_wt + tt*HD + lane*2) = o;
}

// ---- stage a 32x128 bf16 tile into swizzled LDS
__device__ __forceinline__ void stage_bf16(char* Ab, const unsigned short* src, int t){
#pragma unroll
  for(int i=0;i<2;i++){
    int id = t + i*256;
    int row = id>>4, c8 = id&15;
    bf16x8 v = *(const bf16x8*)(src + row*HD + c8*8);
    int byte = row*256 + c8*16;
    *(bf16x8*)(Ab + (byte ^ ((row&7)<<4))) = v;
  }
}

// ---- RGCN + IGAT fused
__global__ __launch_bounds__(256) void krgcn(
    const unsigned short* __restrict__ h_w, const unsigned short* __restrict__ h_t,
    const unsigned short* __restrict__ g_ww, const unsigned short* __restrict__ g_tw,
    const unsigned short* __restrict__ g_wt,
    const unsigned short* __restrict__ Wtb,
    const float* __restrict__ b_worker, const float* __restrict__ b_task,
    const float* __restrict__ a_src, const float* __restrict__ a_dst,
    unsigned short* __restrict__ Wh, float* __restrict__ fs, float* __restrict__ fd,
    float* __restrict__ whsum, float* __restrict__ out_task){
  __shared__ __bf16 As[3][32*HD];    // 24 KB
  __shared__ __bf16 Hs[32*HD];       // 8 KB
  __shared__ float fsp[32][4], fdp[32][4];
  int t = threadIdx.x, lane = t&63, w = t>>6, n0 = w*32;
  bool task = blockIdx.x >= (NWK/32);

  if(!task){
    long r0 = (long)blockIdx.x*32;
    stage_bf16((char*)As[0], h_w  + r0*HD, t);
    stage_bf16((char*)As[1], g_ww + r0*HD, t);
    stage_bf16((char*)As[2], g_tw + r0*HD, t);
    __syncthreads();
    f32x4 acc[2][2] = {};
    const int slot[3] = {2,4,6};     // W_worker, W_ww, W_tw
#pragma unroll
    for(int s=0;s<3;s++){
      const __bf16* Wt = (const __bf16*)(Wtb + (size_t)slot[s]*HD*HD);
      char* Ab = (char*)As[s];
#pragma unroll
      for(int kk=0;kk<4;kk++){
        int kb = kk*32 + (lane>>4)*8;
        bf16x8 bf0 = *(const bf16x8*)(Wt + (n0 +      (lane&15))*HD + kb);
        bf16x8 bf1 = *(const bf16x8*)(Wt + (n0 + 16 + (lane&15))*HD + kb);
#pragma unroll
        for(int m=0;m<2;m++){
          int row = m*16 + (lane&15);
          bf16x8 af = *(const bf16x8*)(Ab + ((row*256 + kb*2) ^ ((row&7)<<4)));
          acc[m][0] = __builtin_amdgcn_mfma_f32_16x16x32_bf16(af, bf0, acc[m][0], 0,0,0);
          acc[m][1] = __builtin_amdgcn_mfma_f32_16x16x32_bf16(af, bf1, acc[m][1], 0,0,0);
        }
      }
    }
    char* HsB = (char*)Hs;
#pragma unroll
    for(int m=0;m<2;m++)
#pragma unroll
    for(int n=0;n<2;n++){
      int col = n0 + n*16 + (lane&15);
      float bc = b_worker[col];
#pragma unroll
      for(int i=0;i<4;i++){
        int row = m*16 + (lane>>4)*4 + i;
        float vv = acc[m][n][i] + bc;
        vv = vv>0.f ? vv : 0.f;
        int byte = row*256 + col*2;
        *(__bf16*)(HsB + (byte ^ ((row&7)<<4))) = (__bf16)vv;
      }
    }
    __syncthreads();
    // stage2: Wh = hwr @ W_igat
    f32x4 acc2[2][2] = {};
    const __bf16* Wt7 = (const __bf16*)(Wtb + (size_t)7*HD*HD);
#pragma unroll
    for(int kk=0;kk<4;kk++){
      int kb = kk*32 + (lane>>4)*8;
      bf16x8 bf0 = *(const bf16x8*)(Wt7 + (n0 +      (lane&15))*HD + kb);
      bf16x8 bf1 = *(const bf16x8*)(Wt7 + (n0 + 16 + (lane&15))*HD + kb);
#pragma unroll
      for(int m=0;m<2;m++){
        int row = m*16 + (lane&15);
        bf16x8 af = *(const bf16x8*)(HsB + ((row*256 + kb*2) ^ ((row&7)<<4)));
        acc2[m][0] = __builtin_amdgcn_mfma_f32_16x16x32_bf16(af, bf0, acc2[m][0], 0,0,0);
        acc2[m][1] = __builtin_amdgcn_mfma_f32_16x16x32_bf16(af, bf1, acc2[m][1], 0,0,0);
      }
    }
#pragma unroll
    for(int m=0;m<2;m++)
#pragma unroll
    for(int n=0;n<2;n++){
      int col = n0 + n*16 + (lane&15);
#pragma unroll
      for(int i=0;i<4;i++){
        long row = r0 + m*16 + (lane>>4)*4 + i;
        Wh[row*HD+col] = f2b(acc2[m][n][i]);
      }
    }
    // fs/fd: per-wave 32-col partials -> LDS -> block reduce, direct store
    float as0 = a_src[n0 + (lane&15)], as1 = a_src[n0 + 16 + (lane&15)];
    float ad0 = a_dst[n0 + (lane&15)], ad1 = a_dst[n0 + 16 + (lane&15)];
#pragma unroll
    for(int m=0;m<2;m++)
#pragma unroll
    for(int i=0;i<4;i++){
      float ps = acc2[m][0][i]*as0 + acc2[m][1][i]*as1;
      float pd = acc2[m][0][i]*ad0 + acc2[m][1][i]*ad1;
#pragma unroll
      for(int o=1;o<16;o<<=1){ ps += __shfl_xor(ps,o,64); pd += __shfl_xor(pd,o,64); }
      if((lane&15)==0){
        int row = m*16 + (lane>>4)*4 + i;
        fsp[row][w] = ps; fdp[row][w] = pd;
      }
    }
    // whsum column partial (deg-0 fallback)
    float c0=0.f, c1=0.f;
#pragma unroll
    for(int m=0;m<2;m++)
#pragma unroll
    for(int i=0;i<4;i++){ c0 += acc2[m][0][i]; c1 += acc2[m][1][i]; }
    c0 += __shfl_xor(c0,16,64); c0 += __shfl_xor(c0,32,64);
    c1 += __shfl_xor(c1,16,64); c1 += __shfl_xor(c1,32,64);
    if(lane<16){
      atomicAdd(&whsum[n0+lane],    c0);
      atomicAdd(&whsum[n0+16+lane], c1);
    }
    __syncthreads();
    if(t < 32){
      fs[r0+t] = fsp[t][0]+fsp[t][1]+fsp[t][2]+fsp[t][3];
      fd[r0+t] = fdp[t][0]+fdp[t][1]+fdp[t][2]+fdp[t][3];
    }
  } else {
    long r0 = (long)(blockIdx.x - (NWK/32))*32;
    stage_bf16((char*)As[0], h_t  + r0*HD, t);
    stage_bf16((char*)As[1], g_wt + r0*HD, t);
    __syncthreads();
    f32x4 acc[2][2] = {};
    const int slot[2] = {3,5};       // W_task, W_wt
#pragma unroll
    for(int s=0;s<2;s++){
      const __bf16* Wt = (const __bf16*)(Wtb + (size_t)slot[s]*HD*HD);
      char* Ab = (char*)As[s];
#pragma unroll
      for(int kk=0;kk<4;kk++){
        int kb = kk*32 + (lane>>4)*8;
        bf16x8 bf0 = *(const bf16x8*)(Wt + (n0 +      (lane&15))*HD + kb);
        bf16x8 bf1 = *(const bf16x8*)(Wt + (n0 + 16 + (lane&15))*HD + kb);
#pragma unroll
        for(int m=0;m<2;m++){
          int row = m*16 + (lane&15);
          bf16x8 af = *(const bf16x8*)(Ab + ((row*256 + kb*2) ^ ((row&7)<<4)));
          acc[m][0] = __builtin_amdgcn_mfma_f32_16x16x32_bf16(af, bf0, acc[m][0], 0,0,0);
          acc[m][1] = __builtin_amdgcn_mfma_f32_16x16x32_bf16(af, bf1, acc[m][1], 0,0,0);
        }
      }
    }
#pragma unroll
    for(int m=0;m<2;m++)
#pragma unroll
    for(int n=0;n<2;n++){
      int col = n0 + n*16 + (lane&15);
      float bc = b_task[col];
#pragma unroll
      for(int i=0;i<4;i++){
        long row = r0 + m*16 + (lane>>4)*4 + i;
        float vv = acc[m][n][i] + bc;
        vv = vv>0.f ? vv : 0.f;
        vv += b2f(h_t[row*HD+col]);
        out_task[row*HD+col] = vv;
      }
    }
  }
}

// ---- sparse masked attention + ELU + residual -> final_worker
__global__ __launch_bounds__(256) void attn(
    const unsigned short* __restrict__ Wh, const float* __restrict__ fs,
    const float* __restrict__ fd, const int* __restrict__ idx,
    const int* __restrict__ deg, const unsigned short* __restrict__ h_w,
    const float* __restrict__ whsum, float* __restrict__ out){
  __shared__ float pa[4][CWW];
  __shared__ int   pj[4][CWW];
  int w = threadIdx.x>>6, lane = threadIdx.x&63;
  long i = (long)blockIdx.x*4 + w;
  int d = deg[i];
  const int* ji = idx + i*CWW;
  float ax=0.f, ay=0.f;
  if(d > 0){
    float fsi = fs[i];
    float m = -1e30f;
    for(int k=lane;k<d;k+=64){
      int j = ji[k]; pj[w][k] = j;
      float e = fsi + fd[j];
      e = e>0.f ? e : 0.2f*e;
      pa[w][k] = e;
      m = fmaxf(m, e);
    }
    m = wredmax(m);
    float ssum = 0.f;
    for(int k=lane;k<d;k+=64){
      float e = __expf(pa[w][k]-m);
      pa[w][k] = e;
      ssum += e;
    }
    ssum = wredsum(ssum);
    float inv = 1.f/ssum;
    int k=0;
    for(; k+3<d; k+=4){
      float a0=pa[w][k], a1=pa[w][k+1], a2=pa[w][k+2], a3=pa[w][k+3];
      long j0=pj[w][k], j1=pj[w][k+1], j2=pj[w][k+2], j3=pj[w][k+3];
      ushort2 u0 = *(const ushort2*)(Wh + j0*HD + lane*2);
      ushort2 u1 = *(const ushort2*)(Wh + j1*HD + lane*2);
      ushort2 u2 = *(const ushort2*)(Wh + j2*HD + lane*2);
      ushort2 u3 = *(const ushort2*)(Wh + j3*HD + lane*2);
      ax += (a0*b2f(u0.x) + a1*b2f(u1.x)) + (a2*b2f(u2.x) + a3*b2f(u3.x));
      ay += (a0*b2f(u0.y) + a1*b2f(u1.y)) + (a2*b2f(u2.y) + a3*b2f(u3.y));
    }
    for(; k<d; ++k){
      float a0 = pa[w][k];
      long j0 = pj[w][k];
      ushort2 u0 = *(const ushort2*)(Wh + j0*HD + lane*2);
      ax += a0*b2f(u0.x);
      ay += a0*b2f(u0.y);
    }
    ax *= inv; ay *= inv;
  } else {
    ax = whsum[lane*2]   * (1.f/8192.f);
    ay = whsum[lane*2+1] * (1.f/8192.f);
  }
  ushort2 r = *(const ushort2*)(h_w + i*HD + lane*2);
  float2 o;
  o.x = (ax>0.f ? ax : __expf(ax)-1.f) + b2f(r.x);
  o.y = (ay>0.f ? ay : __expf(ay)-1.f) + b2f(r.y);
  *(float2*)(out + i*HD + lane*2) = o;
}

extern "C" void kernel_launch(void* const* d_in, const int* in_sizes, int n_in,
                              void* d_out, int out_size, void* d_ws, size_t ws_size,
                              hipStream_t stream){
  const float* Xw       = (const float*)d_in[0];
  const float* Xt       = (const float*)d_in[1];
  const float* WW       = (const float*)d_in[2];
  const float* WT       = (const float*)d_in[3];
  const float* Wp_w     = (const float*)d_in[4];
  const float* bp_w     = (const float*)d_in[5];
  const float* Wp_t     = (const float*)d_in[6];
  const float* bp_t     = (const float*)d_in[7];
  const float* W_worker = (const float*)d_in[8];
  const float* b_worker = (const float*)d_in[9];
  const float* W_task   = (const float*)d_in[10];
  const float* b_task   = (const float*)d_in[11];
  const float* W_ww     = (const float*)d_in[12];
  const float* W_wt     = (const float*)d_in[13];
  const float* W_tw     = (const float*)d_in[14];
  const float* W_igat   = (const float*)d_in[15];
  const float* a_src    = (const float*)d_in[16];
  const float* a_dst    = (const float*)d_in[17];
  float* out = (float*)d_out;

  char* p = (char*)d_ws;
  auto alloc = [&](size_t bytes)->char*{
    char* r = p; p += (bytes + 255) & ~(size_t)255; return r;
  };
  int* ww_idx  = (int*)alloc((size_t)NWK*CWW*4);
  int* wt_idx  = (int*)alloc((size_t)NWK*CWTR*4);
  int* wt_cidx = (int*)alloc((size_t)NTK*CWTC*4);
  int* ww_deg  = (int*)alloc(NWK*4);
  int* wt_deg  = (int*)alloc(NWK*4);
  int*   fill  = (int*)alloc(NTK*4);
  float* whsum = (float*)alloc(512);
  float* fs    = (float*)alloc(NWK*4);
  float* fd    = (float*)alloc(NWK*4);
  unsigned short* h_w  = (unsigned short*)alloc((size_t)NWK*HD*2);
  unsigned short* h_t  = (unsigned short*)alloc((size_t)NTK*HD*2);
  unsigned short* g_ww = (unsigned short*)alloc((size_t)NWK*HD*2);
  unsigned short* g_tw = (unsigned short*)alloc((size_t)NWK*HD*2);
  unsigned short* g_wt = (unsigned short*)alloc((size_t)NTK*HD*2);
  unsigned short* Wh   = (unsigned short*)alloc((size_t)NWK*HD*2);
  unsigned short* Wtb  = (unsigned short*)alloc((size_t)8*HD*HD*2);

  prepw<<<32,256,0,stream>>>(Wp_w, Wp_t, W_worker, W_task, W_ww, W_wt, W_tw, W_igat,
                             Wtb, fill, whsum);
  kproj<<<NWK/32 + NTK/32,256,0,stream>>>(Xw, Xt, Wtb, bp_w, bp_t, h_w, h_t);
  build_all<<<NWK*2,256,0,stream>>>(WW, WT, ww_idx, ww_deg, wt_idx, wt_deg,
                                    wt_cidx, fill, h_w, h_t, g_ww, g_tw);
  agg_csc<<<NTK/4,256,0,stream>>>(h_w, wt_cidx, fill, g_wt);
  krgcn<<<NWK/32 + NTK/32,256,0,stream>>>(h_w, h_t, g_ww, g_tw, g_wt, Wtb,
                                          b_worker, b_task, a_src, a_dst,
                                          Wh, fs, fd, whsum, out + (size_t)NWK*HD);
  attn<<<NWK/4,256,0,stream>>>(Wh, fs, fd, ww_idx, ww_deg, h_w, whsum, out);
}